// Round 1
// baseline (1891.945 us; speedup 1.0000x reference)
//
#include <hip/hip_runtime.h>
#include <hip/hip_bf16.h>

// Flow-matching MLP ODE, 32 midpoint-t Euler steps.
// Design: weights as MFMA A-operands (32x32x16 bf16), activations as B-operands.
// Batch column = lane&31 stays lane-resident across layers; C->B transition via
// v_cvt_pk_bf16_f32 + v_permlane32_swap_b32 (T12). W2 frags in LDS (128KB),
// W1/W3 frags from global (L1/L2-resident). fp32 accum + fp32 x state.

typedef __attribute__((ext_vector_type(8)))  short s16x8;   // 8 bf16 (4 VGPR)
typedef __attribute__((ext_vector_type(16))) float f32x16;  // MFMA acc
typedef __attribute__((ext_vector_type(4)))  float f32x4;

union FragU { s16x8 v; unsigned u[4]; };

__device__ __forceinline__ unsigned cvtpk_bf16(float lo, float hi){
  unsigned r;
  asm("v_cvt_pk_bf16_f32 %0, %1, %2" : "=v"(r) : "v"(lo), "v"(hi));
  return r;
}
__device__ __forceinline__ void plswap32(unsigned &a, unsigned &b){
  // a'[l>=32] = b[l-32]; b'[l<32] = a[l+32]; other halves unchanged.
  asm("v_permlane32_swap_b32 %0, %1" : "+v"(a), "+v"(b));
}

// C-tile (32 features x 32 batch cols, acc layout n=(r&3)+8*(r>>2)+4*g, m=l&31)
// -> two next-layer B-frags: f0 = features [0,16), f1 = [16,32), k-slot = 8g+j.
__device__ __forceinline__ void c_to_b(const f32x16 c, s16x8 &f0, s16x8 &f1){
  unsigned p0 = cvtpk_bf16(c[0],  c[1]);
  unsigned p1 = cvtpk_bf16(c[2],  c[3]);
  unsigned p2 = cvtpk_bf16(c[4],  c[5]);
  unsigned p3 = cvtpk_bf16(c[6],  c[7]);
  plswap32(p0, p2); plswap32(p1, p3);
  FragU a; a.u[0]=p0; a.u[1]=p1; a.u[2]=p2; a.u[3]=p3; f0 = a.v;
  unsigned q0 = cvtpk_bf16(c[8],  c[9]);
  unsigned q1 = cvtpk_bf16(c[10], c[11]);
  unsigned q2 = cvtpk_bf16(c[12], c[13]);
  plswap32(q0, q2);
  unsigned q1b = cvtpk_bf16(c[14], c[15]);
  plswap32(q1, q1b);
  FragU b; b.u[0]=q0; b.u[1]=q1; b.u[2]=q2; b.u[3]=q1b; f1 = b.v;
}

__device__ __forceinline__ float silu_f(float x){
  float e = __builtin_amdgcn_exp2f(x * -1.44269504088896f); // exp(-x)
  return x * __builtin_amdgcn_rcpf(1.0f + e);
}

// ---- setup: pack weights into bf16 A-fragment images in d_ws ----
// frag(Mt,Kt): lane l holds WT[Mt*32 + (l&31)][Kt*16 + 8*(l>>5) + j], j=0..7
// ws shorts: [0,65536): W2 frags (Mt*16+Kt). [65536,81920): W1 (Mt*4+Kt).
//            [81920,98304): W3 (Mt3*16+Kt).
__global__ void setup_kernel(const float* __restrict__ W1,
                             const float* __restrict__ W2,
                             const float* __restrict__ W3,
                             short* __restrict__ ws){
  const int f = blockIdx.x;
  const int l = threadIdx.x;
  const int g = l >> 5, col = l & 31;
  const float* src; int N, Mt, Kt; short* dst;
  if (f < 128)      { Mt = f >> 4;        Kt = f & 15;        src = W2; N = 256; dst = ws + f*512; }
  else if (f < 160) { int id = f - 128;   Mt = id >> 2; Kt = id & 3;  src = W1; N = 256; dst = ws + 65536 + id*512; }
  else              { int id = f - 160;   Mt = id >> 4; Kt = id & 15; src = W3; N = 64;  dst = ws + 81920 + id*512; }
#pragma unroll
  for (int j = 0; j < 8; j++){
    const int k = Kt*16 + 8*g + j;
    const int n = Mt*32 + col;
    float v = src[(size_t)k * N + n];
    __hip_bfloat16 h = __float2bfloat16(v);
    dst[l*8 + j] = *reinterpret_cast<short*>(&h);
  }
}

__launch_bounds__(512, 2)
__global__ void flow_kernel(const float* __restrict__ x0,
                            const float* __restrict__ W1,   // row 64 = t-coefficients
                            const float* __restrict__ b1,
                            const float* __restrict__ b2,
                            const float* __restrict__ b3,
                            const short* __restrict__ ws,
                            float* __restrict__ out){
  extern __shared__ short w2l[];   // 128 KiB of W2 frags
  const int tid = threadIdx.x;
  {
    const int4* src = (const int4*)ws;
    int4* dst = (int4*)w2l;
#pragma unroll
    for (int i = 0; i < 16; i++) dst[tid + i*512] = src[tid + i*512];
  }
  __syncthreads();

  const int lane = tid & 63;
  const int wv   = tid >> 6;
  const int g    = lane >> 5;
  const int m    = lane & 31;
  const int lf   = lane * 8;
  const short* w1f = ws + 65536;
  const short* w3f = ws + 81920;
  const float* w1t = W1 + (size_t)64 * 256;
  const float dt = 1.0f / 32.0f;

  for (int pass = 0; pass < 2; pass++){
    const int rowbase = blockIdx.x * 512 + (wv*2 + pass) * 32;
    const float* xin = x0 + (size_t)(rowbase + m) * 64;

    // x state in C3 layout: xr[t][4q+i] = x[row m][32t + 8q + 4g + i]
    f32x16 xr[2];
#pragma unroll
    for (int t = 0; t < 2; t++)
#pragma unroll
      for (int q = 0; q < 4; q++){
        f32x4 v = *(const f32x4*)(xin + t*32 + q*8 + g*4);
#pragma unroll
        for (int i = 0; i < 4; i++) xr[t][q*4+i] = v[i];
      }

    s16x8 b1f[4];
    c_to_b(xr[0], b1f[0], b1f[1]);
    c_to_b(xr[1], b1f[2], b1f[3]);

#pragma unroll 1
    for (int s = 0; s < 32; s++){
      const float tv = ((float)s + 0.5f) * (1.0f / 32.0f);

      // ---- layer 1: h1 = silu(x@W1[:64] + t*W1[64] + b1) ----
      s16x8 b2f[16];
#pragma unroll
      for (int Mt = 0; Mt < 8; Mt++){
        f32x16 acc;
#pragma unroll
        for (int q = 0; q < 4; q++){
          f32x4 bv = *(const f32x4*)(b1  + Mt*32 + q*8 + g*4);
          f32x4 wv4 = *(const f32x4*)(w1t + Mt*32 + q*8 + g*4);
#pragma unroll
          for (int i = 0; i < 4; i++) acc[q*4+i] = bv[i] + tv * wv4[i];
        }
#pragma unroll
        for (int kt = 0; kt < 4; kt++){
          s16x8 af = *(const s16x8*)(w1f + (Mt*4 + kt)*512 + lf);
          acc = __builtin_amdgcn_mfma_f32_32x32x16_bf16(af, b1f[kt], acc, 0, 0, 0);
        }
#pragma unroll
        for (int i = 0; i < 16; i++) acc[i] = silu_f(acc[i]);
        c_to_b(acc, b2f[2*Mt], b2f[2*Mt+1]);
      }

      // ---- layer 2 (+fused layer 3): v = silu(h1@W2+b2)@W3 + b3 ----
      f32x16 c3[2];
#pragma unroll
      for (int t3 = 0; t3 < 2; t3++)
#pragma unroll
        for (int q = 0; q < 4; q++){
          f32x4 bv = *(const f32x4*)(b3 + t3*32 + q*8 + g*4);
#pragma unroll
          for (int i = 0; i < 4; i++) c3[t3][q*4+i] = bv[i];
        }
#pragma unroll
      for (int Mt = 0; Mt < 8; Mt++){
        f32x16 acc;
#pragma unroll
        for (int q = 0; q < 4; q++){
          f32x4 bv = *(const f32x4*)(b2 + Mt*32 + q*8 + g*4);
#pragma unroll
          for (int i = 0; i < 4; i++) acc[q*4+i] = bv[i];
        }
#pragma unroll
        for (int kt = 0; kt < 16; kt++){
          s16x8 af = *(const s16x8*)(w2l + (Mt*16 + kt)*512 + lf);
          acc = __builtin_amdgcn_mfma_f32_32x32x16_bf16(af, b2f[kt], acc, 0, 0, 0);
        }
#pragma unroll
        for (int i = 0; i < 16; i++) acc[i] = silu_f(acc[i]);
        s16x8 f0, f1;
        c_to_b(acc, f0, f1);
#pragma unroll
        for (int t3 = 0; t3 < 2; t3++){
          s16x8 a0 = *(const s16x8*)(w3f + (t3*16 + 2*Mt    )*512 + lf);
          s16x8 a1 = *(const s16x8*)(w3f + (t3*16 + 2*Mt + 1)*512 + lf);
          c3[t3] = __builtin_amdgcn_mfma_f32_32x32x16_bf16(a0, f0, c3[t3], 0, 0, 0);
          c3[t3] = __builtin_amdgcn_mfma_f32_32x32x16_bf16(a1, f1, c3[t3], 0, 0, 0);
        }
      }

      // ---- x += dt * v ; rebuild x B-frags ----
#pragma unroll
      for (int t = 0; t < 2; t++)
#pragma unroll
        for (int i = 0; i < 16; i++) xr[t][i] += dt * c3[t][i];
      c_to_b(xr[0], b1f[0], b1f[1]);
      c_to_b(xr[1], b1f[2], b1f[3]);
    }

    float* xo = out + (size_t)(rowbase + m) * 64;
#pragma unroll
    for (int t = 0; t < 2; t++)
#pragma unroll
      for (int q = 0; q < 4; q++){
        f32x4 v;
#pragma unroll
        for (int i = 0; i < 4; i++) v[i] = xr[t][q*4+i];
        *(f32x4*)(xo + t*32 + q*8 + g*4) = v;
      }
  }
}

extern "C" void kernel_launch(void* const* d_in, const int* in_sizes, int n_in,
                              void* d_out, int out_size, void* d_ws, size_t ws_size,
                              hipStream_t stream){
  const float* x0 = (const float*)d_in[0];
  const float* W1 = (const float*)d_in[1];
  const float* b1 = (const float*)d_in[2];
  const float* W2 = (const float*)d_in[3];
  const float* b2 = (const float*)d_in[4];
  const float* W3 = (const float*)d_in[5];
  const float* b3 = (const float*)d_in[6];
  short* ws  = (short*)d_ws;
  float* out = (float*)d_out;
  (void)in_sizes; (void)n_in; (void)out_size; (void)ws_size;

  hipFuncSetAttribute((const void*)flow_kernel,
                      hipFuncAttributeMaxDynamicSharedMemorySize, 131072);

  setup_kernel<<<192, 64, 0, stream>>>(W1, W2, W3, ws);
  flow_kernel<<<256, 512, 131072, stream>>>(x0, W1, b1, b2, b3, ws, out);
}

// Round 2
// 1064.008 us; speedup vs baseline: 1.7781x; 1.7781x over previous
//
#include <hip/hip_runtime.h>
#include <hip/hip_bf16.h>

// Flow-matching MLP ODE, 32 midpoint-t Euler steps.
// Weights as MFMA A-operands (32x32x16 bf16), activations as B-operands.
// Batch column = lane&31 stays lane-resident across layers; C->B transition via
// v_cvt_pk_bf16_f32 + v_permlane32_swap_b32 (T12).
// R2: W2+W1 frags in LDS (160KB exactly); biases + t-term folded into MFMA
// (A-frag bias rows x B-frag [t,1,0..]); W3 from global (L1-resident, per-Mt
// prefetch window). fp32 accum + fp32 x state.

typedef __attribute__((ext_vector_type(8)))  short s16x8;   // 8 bf16 (4 VGPR)
typedef __attribute__((ext_vector_type(16))) float f32x16;  // MFMA acc
typedef __attribute__((ext_vector_type(4)))  float f32x4;

union FragU { s16x8 v; unsigned u[4]; };

__device__ __forceinline__ unsigned cvtpk_bf16(float lo, float hi){
  unsigned r;
  asm("v_cvt_pk_bf16_f32 %0, %1, %2" : "=v"(r) : "v"(lo), "v"(hi));
  return r;
}
__device__ __forceinline__ void plswap32(unsigned &a, unsigned &b){
  asm("v_permlane32_swap_b32 %0, %1" : "+v"(a), "+v"(b));
}

// C-tile (acc layout n=(r&3)+8*(r>>2)+4*g, m=l&31) -> two next-layer B-frags.
__device__ __forceinline__ void c_to_b(const f32x16 c, s16x8 &f0, s16x8 &f1){
  unsigned p0 = cvtpk_bf16(c[0],  c[1]);
  unsigned p1 = cvtpk_bf16(c[2],  c[3]);
  unsigned p2 = cvtpk_bf16(c[4],  c[5]);
  unsigned p3 = cvtpk_bf16(c[6],  c[7]);
  plswap32(p0, p2); plswap32(p1, p3);
  FragU a; a.u[0]=p0; a.u[1]=p1; a.u[2]=p2; a.u[3]=p3; f0 = a.v;
  unsigned q0 = cvtpk_bf16(c[8],  c[9]);
  unsigned q1 = cvtpk_bf16(c[10], c[11]);
  unsigned q2 = cvtpk_bf16(c[12], c[13]);
  plswap32(q0, q2);
  unsigned q1b = cvtpk_bf16(c[14], c[15]);
  plswap32(q1, q1b);
  FragU b; b.u[0]=q0; b.u[1]=q1; b.u[2]=q2; b.u[3]=q1b; f1 = b.v;
}

__device__ __forceinline__ float silu_f(float x){
  float e = __builtin_amdgcn_exp2f(x * -1.44269504088896f); // exp(-x)
  return x * __builtin_amdgcn_rcpf(1.0f + e);
}

// ---- setup: pack weights + bias frags (bf16 A-fragment images) into d_ws ----
// frag(Mt,Kt): lane l holds WT[Mt*32 + (l&31)][Kt*16 + 8*(l>>5) + j], j=0..7
// ws shorts: [0,65536) W2 frags. [65536,81920) W1. [81920,98304) W3.
//            [98304,102400) t1-frags (k0=W1[64] t-row, k1=b1).
//            [102400,106496) b2-frags (k0=b2). [106496,107520) b3-frags (k0=b3).
__global__ void setup_kernel(const float* __restrict__ W1,
                             const float* __restrict__ b1,
                             const float* __restrict__ W2,
                             const float* __restrict__ b2,
                             const float* __restrict__ W3,
                             const float* __restrict__ b3,
                             short* __restrict__ ws){
  const int f = blockIdx.x;
  const int l = threadIdx.x;
  const int g = l >> 5, col = l & 31;

  if (f < 192){
    const float* src; int N, Mt, Kt; short* dst;
    if (f < 128)      { Mt = f >> 4;      Kt = f & 15;       src = W2; N = 256; dst = ws + f*512; }
    else if (f < 160) { int id = f - 128; Mt = id >> 2; Kt = id & 3;  src = W1; N = 256; dst = ws + 65536 + id*512; }
    else              { int id = f - 160; Mt = id >> 4; Kt = id & 15; src = W3; N = 64;  dst = ws + 81920 + id*512; }
#pragma unroll
    for (int j = 0; j < 8; j++){
      const int k = Kt*16 + 8*g + j;
      const int n = Mt*32 + col;
      float v = src[(size_t)k * N + n];
      __hip_bfloat16 h = __float2bfloat16(v);
      dst[l*8 + j] = *reinterpret_cast<short*>(&h);
    }
  } else {
    // bias fragments
    short* dst; int Mt; int kind;
    if (f < 200)      { kind = 0; Mt = f - 192; dst = ws + 98304  + Mt*512; }
    else if (f < 208) { kind = 1; Mt = f - 200; dst = ws + 102400 + Mt*512; }
    else              { kind = 2; Mt = f - 208; dst = ws + 106496 + Mt*512; }
    const int n = Mt*32 + col;
#pragma unroll
    for (int j = 0; j < 8; j++){
      const int k = 8*g + j;
      float v = 0.0f;
      if (kind == 0){
        if (k == 0) v = W1[(size_t)64*256 + n];   // t-coefficient row
        else if (k == 1) v = b1[n];
      } else if (kind == 1){
        if (k == 0) v = b2[n];
      } else {
        if (k == 0) v = b3[n];
      }
      __hip_bfloat16 h = __float2bfloat16(v);
      dst[l*8 + j] = *reinterpret_cast<short*>(&h);
    }
  }
}

__launch_bounds__(512, 2)
__global__ void flow_kernel(const float* __restrict__ x0,
                            const short* __restrict__ ws,
                            float* __restrict__ out){
  extern __shared__ short lds[];   // 160 KiB: W2 frags [0,65536), W1 frags [65536,81920)
  const int tid = threadIdx.x;
  {
    const int4* src = (const int4*)ws;
    int4* dst = (int4*)lds;
#pragma unroll
    for (int i = 0; i < 20; i++) dst[tid + i*512] = src[tid + i*512];
  }
  __syncthreads();

  const short* w2l = lds;
  const short* w1l = lds + 65536;
  const short* w3f = ws + 81920;
  const short* t1g = ws + 98304;
  const short* b2g = ws + 102400;
  const short* b3g = ws + 106496;

  const int lane = tid & 63;
  const int wv   = tid >> 6;
  const int g    = lane >> 5;
  const int m    = lane & 31;
  const int lf   = lane * 8;
  const float dt = 1.0f / 32.0f;

  // persistent: t1 fragments (t-row + b1), the ones-B-frag, zero acc
  s16x8 t1f[8];
#pragma unroll
  for (int Mt = 0; Mt < 8; Mt++) t1f[Mt] = *(const s16x8*)(t1g + Mt*512 + lf);
  s16x8 onef;
  { FragU o; o.u[0] = (g==0) ? cvtpk_bf16(1.0f, 0.0f) : 0u; o.u[1]=0u; o.u[2]=0u; o.u[3]=0u; onef = o.v; }
  const f32x16 zf = {0.f,0.f,0.f,0.f,0.f,0.f,0.f,0.f,0.f,0.f,0.f,0.f,0.f,0.f,0.f,0.f};

  for (int pass = 0; pass < 2; pass++){
    const int rowbase = blockIdx.x * 512 + (wv*2 + pass) * 32;
    const float* xin = x0 + (size_t)(rowbase + m) * 64;

    // x state in C layout: xr[t][4q+i] = x[row m][32t + 8q + 4g + i]
    f32x16 xr[2];
#pragma unroll
    for (int t = 0; t < 2; t++)
#pragma unroll
      for (int q = 0; q < 4; q++){
        f32x4 v = *(const f32x4*)(xin + t*32 + q*8 + g*4);
#pragma unroll
        for (int i = 0; i < 4; i++) xr[t][q*4+i] = v[i];
      }

    s16x8 b1f[4];
    c_to_b(xr[0], b1f[0], b1f[1]);
    c_to_b(xr[1], b1f[2], b1f[3]);

#pragma unroll 1
    for (int s = 0; s < 32; s++){
      const float tv = ((float)s + 0.5f) * (1.0f / 32.0f);
      s16x8 tf;
      { FragU o; o.u[0] = (g==0) ? cvtpk_bf16(tv, 1.0f) : 0u; o.u[1]=0u; o.u[2]=0u; o.u[3]=0u; tf = o.v; }

      // issue bias-frag loads now; consumed one layer later (latency hidden)
      s16x8 b2A[8], b3A[2];
#pragma unroll
      for (int Mt = 0; Mt < 8; Mt++) b2A[Mt] = *(const s16x8*)(b2g + Mt*512 + lf);
      b3A[0] = *(const s16x8*)(b3g + lf);
      b3A[1] = *(const s16x8*)(b3g + 512 + lf);

      // ---- layer 1: h1 = silu(x@W1x + t*W1t + b1), bias via t1f x tf ----
      s16x8 b2f[16];
#pragma unroll
      for (int Mt = 0; Mt < 8; Mt++){
        f32x16 acc = __builtin_amdgcn_mfma_f32_32x32x16_bf16(t1f[Mt], tf, zf, 0, 0, 0);
#pragma unroll
        for (int kt = 0; kt < 4; kt++){
          s16x8 af = *(const s16x8*)(w1l + (Mt*4 + kt)*512 + lf);
          acc = __builtin_amdgcn_mfma_f32_32x32x16_bf16(af, b1f[kt], acc, 0, 0, 0);
        }
#pragma unroll
        for (int i = 0; i < 16; i++) acc[i] = silu_f(acc[i]);
        c_to_b(acc, b2f[2*Mt], b2f[2*Mt+1]);
      }

      // ---- layer 2 (+fused layer 3): v = silu(h1@W2+b2)@W3 + b3 ----
      f32x16 c3[2];
      c3[0] = __builtin_amdgcn_mfma_f32_32x32x16_bf16(b3A[0], onef, zf, 0, 0, 0);
      c3[1] = __builtin_amdgcn_mfma_f32_32x32x16_bf16(b3A[1], onef, zf, 0, 0, 0);
#pragma unroll
      for (int Mt = 0; Mt < 8; Mt++){
        // W3 frag loads issued at iteration top; used after the MFMA+silu chain
        s16x8 w3a = *(const s16x8*)(w3f + (2*Mt    )*512 + lf);
        s16x8 w3b = *(const s16x8*)(w3f + (2*Mt + 1)*512 + lf);
        s16x8 w3c = *(const s16x8*)(w3f + (16 + 2*Mt)*512 + lf);
        s16x8 w3d = *(const s16x8*)(w3f + (17 + 2*Mt)*512 + lf);

        f32x16 a2 = __builtin_amdgcn_mfma_f32_32x32x16_bf16(b2A[Mt], onef, zf, 0, 0, 0);
#pragma unroll
        for (int kt = 0; kt < 16; kt++){
          s16x8 af = *(const s16x8*)(w2l + (Mt*16 + kt)*512 + lf);
          a2 = __builtin_amdgcn_mfma_f32_32x32x16_bf16(af, b2f[kt], a2, 0, 0, 0);
        }
#pragma unroll
        for (int i = 0; i < 16; i++) a2[i] = silu_f(a2[i]);
        s16x8 f0, f1;
        c_to_b(a2, f0, f1);
        c3[0] = __builtin_amdgcn_mfma_f32_32x32x16_bf16(w3a, f0, c3[0], 0, 0, 0);
        c3[0] = __builtin_amdgcn_mfma_f32_32x32x16_bf16(w3b, f1, c3[0], 0, 0, 0);
        c3[1] = __builtin_amdgcn_mfma_f32_32x32x16_bf16(w3c, f0, c3[1], 0, 0, 0);
        c3[1] = __builtin_amdgcn_mfma_f32_32x32x16_bf16(w3d, f1, c3[1], 0, 0, 0);
      }

      // ---- x += dt * v ; rebuild x B-frags ----
#pragma unroll
      for (int t = 0; t < 2; t++)
#pragma unroll
        for (int i = 0; i < 16; i++) xr[t][i] += dt * c3[t][i];
      c_to_b(xr[0], b1f[0], b1f[1]);
      c_to_b(xr[1], b1f[2], b1f[3]);
    }

    float* xo = out + (size_t)(rowbase + m) * 64;
#pragma unroll
    for (int t = 0; t < 2; t++)
#pragma unroll
      for (int q = 0; q < 4; q++){
        f32x4 v;
#pragma unroll
        for (int i = 0; i < 4; i++) v[i] = xr[t][q*4+i];
        *(f32x4*)(xo + t*32 + q*8 + g*4) = v;
      }
  }
}

extern "C" void kernel_launch(void* const* d_in, const int* in_sizes, int n_in,
                              void* d_out, int out_size, void* d_ws, size_t ws_size,
                              hipStream_t stream){
  const float* x0 = (const float*)d_in[0];
  const float* W1 = (const float*)d_in[1];
  const float* b1 = (const float*)d_in[2];
  const float* W2 = (const float*)d_in[3];
  const float* b2 = (const float*)d_in[4];
  const float* W3 = (const float*)d_in[5];
  const float* b3 = (const float*)d_in[6];
  short* ws  = (short*)d_ws;
  float* out = (float*)d_out;
  (void)in_sizes; (void)n_in; (void)out_size; (void)ws_size;

  hipFuncSetAttribute((const void*)flow_kernel,
                      hipFuncAttributeMaxDynamicSharedMemorySize, 163840);

  setup_kernel<<<210, 64, 0, stream>>>(W1, b1, W2, b2, W3, b3, ws);
  flow_kernel<<<256, 512, 163840, stream>>>(x0, ws, out);
}